// Round 3
// baseline (297.291 us; speedup 1.0000x reference)
//
#include <hip/hip_runtime.h>
#include <hip/hip_bf16.h>
#include <stdint.h>

typedef unsigned short u16;
typedef __attribute__((ext_vector_type(4))) float f32x4;
typedef __attribute__((ext_vector_type(8))) short bf16x8;
typedef __attribute__((ext_vector_type(4))) unsigned short u16x4;
typedef __attribute__((ext_vector_type(8))) unsigned short u16x8;

// round-to-nearest-even f32 -> bf16
__device__ inline u16 f2bf(float f) {
    unsigned int u = __builtin_bit_cast(unsigned int, f);
    u = u + 0x7fffu + ((u >> 16) & 1u);
    return (u16)(u >> 16);
}
__device__ inline float bf2f(u16 h) {
    return __builtin_bit_cast(float, ((unsigned int)h) << 16);
}

// async global->LDS, 16B per lane. LDS dest is wave-uniform base + lane*16.
__device__ inline void gld_lds16(const void* g, void* l) {
    __builtin_amdgcn_global_load_lds((__attribute__((address_space(1))) void*)(g),
                                     (__attribute__((address_space(3))) void*)(l),
                                     16, 0, 0);
}

// ---------------------------------------------------------------------------
// Generic NT GEMM: C[i,j] = scale * sum_k A[i,k]*B[j,k]  (+ bias[j])
// A: [M,K] row-major (lda), bf16 (AF32=0) or f32 (AF32=1, converted on the fly)
// B: [N,K] bf16 row-major (ldb)
// 128x128 tile, BK=64, 256 threads = 4 waves (2x2), 64x64 per wave.
// LDS physical layout: row r (128B), physical 16B-chunk p holds logical chunk
// p ^ (r&7). bf16 path: linear LDS dest (global_load_lds) + pre-swizzled
// global source. f32 path: reg-stage + ds_write_b128 to swizzled dest.
// Reads apply the same XOR. (both-sides-or-neither, guide G21)
// ---------------------------------------------------------------------------
template <int BF16OUT, int BIAS, int AF32>
__global__ __launch_bounds__(256, 2)
void gemm_nt(const void* __restrict__ Av, const u16* __restrict__ B,
             void* __restrict__ Cv, const float* __restrict__ bias,
             int K, int lda, int ldb, int ldc,
             long sAb, long sBb, long sCb, float scale)
{
    __shared__ __align__(16) u16 shA[128 * 64];
    __shared__ __align__(16) u16 shB[128 * 64];

    const int    zb = blockIdx.z;
    const u16*   Au = (const u16*)Av + zb * sAb;
    const float* Af = (const float*)Av + zb * sAb;
    const u16*   Bb = B + zb * sBb;

    const int tid  = threadIdx.x;
    const int lane = tid & 63;
    const int w    = tid >> 6;          // wave 0..3
    const int wm   = w >> 1, wn = w & 1;
    const long rowA0 = (long)blockIdx.x * 128;
    const long rowB0 = (long)blockIdx.y * 128;

    // staging geometry: wave w, call i covers rows w*32+i*8 + (lane>>3)
    const int srow   = w * 32 + (lane >> 3);
    const int schunk = (lane & 7) ^ ((lane >> 3) & 7);  // r&7 == (lane>>3)&7

    f32x4 acc[4][4] = {};

    for (int k0 = 0; k0 < K; k0 += 64) {
        if (AF32) {
#pragma unroll
            for (int i = 0; i < 4; ++i) {
                const int r = srow + i * 8;
                const float* s = Af + (rowA0 + r) * (long)lda + k0 + (lane & 7) * 8;
                f32x4 v0 = *(const f32x4*)s;
                f32x4 v1 = *(const f32x4*)(s + 4);
                u16x8 o;
#pragma unroll
                for (int j = 0; j < 4; ++j) { o[j] = f2bf(v0[j]); o[4 + j] = f2bf(v1[j]); }
                *(u16x8*)((char*)shA + r * 128 + (schunk << 4)) = o;
            }
        } else {
#pragma unroll
            for (int i = 0; i < 4; ++i)
                gld_lds16(Au + (rowA0 + srow + i * 8) * (long)lda + k0 + schunk * 8,
                          (char*)shA + w * 4096 + i * 1024);
        }
#pragma unroll
        for (int i = 0; i < 4; ++i)
            gld_lds16(Bb + (rowB0 + srow + i * 8) * (long)ldb + k0 + schunk * 8,
                      (char*)shB + w * 4096 + i * 1024);
        __syncthreads();
#pragma unroll
        for (int kk = 0; kk < 64; kk += 32) {
            bf16x8 af[4], bfv[4];
#pragma unroll
            for (int m = 0; m < 4; ++m) {
                const int row = wm * 64 + m * 16 + (lane & 15);
                const int byt = (kk * 2 + (lane >> 4) * 16) ^ ((row & 7) << 4);
                af[m] = *(const bf16x8*)((const char*)shA + row * 128 + byt);
            }
#pragma unroll
            for (int n = 0; n < 4; ++n) {
                const int row = wn * 64 + n * 16 + (lane & 15);
                const int byt = (kk * 2 + (lane >> 4) * 16) ^ ((row & 7) << 4);
                bfv[n] = *(const bf16x8*)((const char*)shB + row * 128 + byt);
            }
#pragma unroll
            for (int m = 0; m < 4; ++m)
#pragma unroll
                for (int n = 0; n < 4; ++n)
                    acc[m][n] = __builtin_amdgcn_mfma_f32_16x16x32_bf16(
                        af[m], bfv[n], acc[m][n], 0, 0, 0);
        }
        __syncthreads();
    }

    // epilogue: C/D layout col = lane&15, row = (lane>>4)*4 + j   [m89/m91]
#pragma unroll
    for (int m = 0; m < 4; ++m) {
#pragma unroll
        for (int n = 0; n < 4; ++n) {
            const long row0 = rowA0 + wm * 64 + m * 16 + (lane >> 4) * 4;
            const long col  = rowB0 + wn * 64 + n * 16 + (lane & 15);
            float bv = 0.0f;
            if (BIAS) bv = bias[col];
#pragma unroll
            for (int j = 0; j < 4; ++j) {
                const float val = acc[m][n][j] * scale + bv;
                const long  idx = (long)zb * sCb + (row0 + j) * ldc + col;
                if (BF16OUT) ((u16*)Cv)[idx] = f2bf(val);
                else         ((float*)Cv)[idx] = val;
            }
        }
    }
}

// ---------------------------------------------------------------------------
// In-place row softmax over 2048 bf16. One block (256 thr) per row.
// ---------------------------------------------------------------------------
__global__ __launch_bounds__(256)
void softmax_rows_bf16(u16* __restrict__ sc)
{
    __shared__ float redmax[4];
    __shared__ float redsum[4];
    const long row = blockIdx.x;
    u16x8* p = (u16x8*)(sc + row * 2048);
    const int t = threadIdx.x;

    u16x8 v = p[t];
    float f[8];
#pragma unroll
    for (int j = 0; j < 8; ++j) f[j] = bf2f(v[j]);

    float m = f[0];
#pragma unroll
    for (int j = 1; j < 8; ++j) m = fmaxf(m, f[j]);
#pragma unroll
    for (int o = 32; o; o >>= 1) m = fmaxf(m, __shfl_xor(m, o));
    if ((t & 63) == 0) redmax[t >> 6] = m;
    __syncthreads();
    m = fmaxf(fmaxf(redmax[0], redmax[1]), fmaxf(redmax[2], redmax[3]));

    float e[8], s = 0.0f;
#pragma unroll
    for (int j = 0; j < 8; ++j) { e[j] = __expf(f[j] - m); s += e[j]; }
#pragma unroll
    for (int o = 32; o; o >>= 1) s += __shfl_xor(s, o);
    if ((t & 63) == 0) redsum[t >> 6] = s;
    __syncthreads();
    s = redsum[0] + redsum[1] + redsum[2] + redsum[3];
    const float inv = 1.0f / s;

    u16x8 o;
#pragma unroll
    for (int j = 0; j < 8; ++j) o[j] = f2bf(e[j] * inv);
    p[t] = o;
}

// f32 -> bf16 elementwise, 4 elems/thread
__global__ __launch_bounds__(256)
void cvt_bf16(const float* __restrict__ src, u16* __restrict__ dst, long n4)
{
    const long i = (long)blockIdx.x * 256 + threadIdx.x;
    if (i >= n4) return;
    f32x4 v = ((const f32x4*)src)[i];
    u16x4 o;
#pragma unroll
    for (int j = 0; j < 4; ++j) o[j] = f2bf(v[j]);
    ((u16x4*)dst)[i] = o;
}

// x[b][n][d] f32 -> xT[b][d][n] bf16, 32x32 LDS tiles
__global__ __launch_bounds__(256)
void transpose_x(const float* __restrict__ x, u16* __restrict__ xT)
{
    __shared__ float tile[32][33];
    const int  b  = blockIdx.z;
    const long n0 = (long)blockIdx.x * 32;
    const long d0 = (long)blockIdx.y * 32;
    const int  t  = threadIdx.x;
    const int  r  = t >> 3;
    const int  c  = (t & 7) * 4;

    f32x4 v = *(const f32x4*)(x + ((long)b * 2048 + n0 + r) * 1024 + d0 + c);
#pragma unroll
    for (int j = 0; j < 4; ++j) tile[r][c + j] = v[j];
    __syncthreads();

    u16x4 o;
#pragma unroll
    for (int j = 0; j < 4; ++j) o[j] = f2bf(tile[c + j][r]);
    *(u16x4*)(xT + ((long)b * 1024 + d0 + r) * 2048 + n0 + c) = o;
}

// ---------------------------------------------------------------------------
// B=8, N=2048, DIM=1024
// ws layout (bytes), total 164 MB:
//   xT [8,1024,2048] bf16 @ 0         (32 MB)  live: transpose -> PV
//   Wb [2048,1024]   bf16 @ 32 MB     ( 4 MB)  live: cvt -> proj
//   qk [16384,2048]  bf16 @ 36 MB     (64 MB)  live: proj -> scores
//   sc [8,2048,2048] bf16 @ 100 MB    (64 MB)  scores out, softmax in-place, PV in
// ---------------------------------------------------------------------------
extern "C" void kernel_launch(void* const* d_in, const int* in_sizes, int n_in,
                              void* d_out, int out_size, void* d_ws, size_t ws_size,
                              hipStream_t stream)
{
    const float* x   = (const float*)d_in[0];
    const float* Wqk = (const float*)d_in[1];
    const float* bqk = (const float*)d_in[2];
    float* out = (float*)d_out;

    char* ws = (char*)d_ws;
    u16* xT = (u16*)(ws);
    u16* Wb = (u16*)(ws + 33554432L);
    u16* qk = (u16*)(ws + 37748736L);
    u16* sc = (u16*)(ws + 104857600L);

    cvt_bf16<<<2048, 256, 0, stream>>>(Wqk, Wb, 2048L * 1024 / 4);
    transpose_x<<<dim3(64, 32, 8), 256, 0, stream>>>(x, xT);

    // qk = x @ W^T + b   (A = f32 x, converted in staging) -> bf16 [16384, 2048]
    gemm_nt<1, 1, 1><<<dim3(128, 16, 1), 256, 0, stream>>>(
        x, Wb, qk, bqk, 1024, 1024, 1024, 2048, 0, 0, 0, 1.0f);

    // sc[b] = k_b @ q_b^T / 32  -> bf16 [2048, 2048] per batch
    gemm_nt<1, 0, 0><<<dim3(16, 16, 8), 256, 0, stream>>>(
        qk + 1024, qk, sc, nullptr, 1024, 2048, 2048, 2048,
        2048L * 2048, 2048L * 2048, 2048L * 2048, 0.03125f);

    // sc = softmax(sc) in place
    softmax_rows_bf16<<<16384, 256, 0, stream>>>(sc);

    // out[b] = attn_b @ x_b  (NT with xT) -> f32 to d_out
    gemm_nt<0, 0, 0><<<dim3(16, 8, 8), 256, 0, stream>>>(
        sc, xT, out, nullptr, 2048, 2048, 2048, 1024,
        2048L * 2048, 1024L * 2048, 2048L * 1024, 1.0f);
}

// Round 4
// 271.196 us; speedup vs baseline: 1.0962x; 1.0962x over previous
//
#include <hip/hip_runtime.h>
#include <hip/hip_bf16.h>
#include <stdint.h>

typedef unsigned short u16;
typedef __attribute__((ext_vector_type(4))) float f32x4;
typedef __attribute__((ext_vector_type(8))) short bf16x8;
typedef __attribute__((ext_vector_type(4))) unsigned short u16x4;
typedef __attribute__((ext_vector_type(8))) unsigned short u16x8;

__device__ inline u16 f2bf(float f) {
    unsigned int u = __builtin_bit_cast(unsigned int, f);
    u = u + 0x7fffu + ((u >> 16) & 1u);
    return (u16)(u >> 16);
}
__device__ inline float bf2f(u16 h) {
    return __builtin_bit_cast(float, ((unsigned int)h) << 16);
}
__device__ inline void gld_lds16(const void* g, void* l) {
    __builtin_amdgcn_global_load_lds((__attribute__((address_space(1))) void*)(g),
                                     (__attribute__((address_space(3))) void*)(l),
                                     16, 0, 0);
}

#define BARRIER() do { __builtin_amdgcn_s_barrier(); __builtin_amdgcn_sched_barrier(0); } while (0)
#define LGKM0()   do { asm volatile("s_waitcnt lgkmcnt(0)" ::: "memory"); \
                       __builtin_amdgcn_sched_barrier(0); } while (0)

// ---------------------------------------------------------------------------
// 256x256 NT GEMM, BK=64, 512 thr = 8 waves (2M x 4N), 128x64 out per wave.
// 8-phase schedule (4 phases/K-tile), counted vmcnt (T3+T4), setprio (T5),
// XOR-swizzled LDS (T2) via pre-swizzled global source + swizzled ds_read,
// bijective XCD swizzle (T1). LDS = 2 x (A 32KB + B 32KB) = 128 KB.
//
// Per-tile phase p: [ds_reads][stage 1 half][barrier][lgkm0][prio1][16 MFMA]
// [prio0][(p==3: vmcnt(4))][barrier].
// ds_reads: ph0 a0[m0-3]+b0[n0-1] (12), ph1 a1[m4-7] (8), ph2 b1[n2-3] (4).
// stage: ph0 B0(t+1), ph1 B1(t+1), ph2 A0(t+2), ph3 A1(t+2).
// Safety: B(t+1) overwrites buf[t+1] whose last reads retired at (t-1,ph2);
// A(t+2) overwrites buf[t] A-regions whose reads retired by (t,ph1) lgkm.
// vmcnt(4) at boundary forces all 4 halves of tile t+1 (leaves A(t+2) pair).
// Tail (t >= NT-2): stages no-op so drain with vmcnt(0).
// ---------------------------------------------------------------------------
template <int BF16OUT, int BIAS>
__global__ __launch_bounds__(512, 2)
void gemm256(const u16* __restrict__ A, const u16* __restrict__ B,
             void* __restrict__ Cv, const float* __restrict__ bias,
             int K, int lda, int ldb, int ldc,
             long sAb, long sBb, long sCb, float scale)
{
    __shared__ __align__(16) char lds[131072];

    const int tid  = threadIdx.x;
    const int lane = tid & 63;
    const int w    = tid >> 6;
    const int wm   = w >> 2, wn = w & 3;

    // XCD-aware bijective block swizzle (nwg % 8 == 0 for all our grids)
    const int gx   = gridDim.x, gy = gridDim.y;
    const int flat = blockIdx.x + gx * (blockIdx.y + gy * blockIdx.z);
    const int nwg  = gx * gy * gridDim.z;
    const int swz  = (flat & 7) * (nwg >> 3) + (flat >> 3);
    const int mt   = swz % gx;
    const int rest = swz / gx;
    const int ntl  = rest % gy;
    const int zb   = rest / gy;

    const u16* Ab = A + (long)zb * sAb;
    const u16* Bb = B + (long)zb * sBb;
    const long rowA0 = (long)mt * 256;
    const long rowB0 = (long)ntl * 256;

    // staging geometry: wave w covers rows w*16 + j*8 + (lane>>3) of each half
    const int srow   = w * 16 + (lane >> 3);
    const int schunk = (lane & 7) ^ ((lane >> 3) & 7);
    const u16* aG = Ab + (rowA0 + srow) * (long)lda + schunk * 8;
    const u16* bG = Bb + (rowB0 + srow) * (long)ldb + schunk * 8;

    const int NT = K >> 6;

    auto stageA = [&](int t, int hh) {
        if (t >= NT) return;
        const u16* s = aG + (long)hh * 128 * lda + (long)t * 64;
        char* d = lds + (t & 1) * 65536 + hh * 16384 + w * 2048;
        gld_lds16(s, d);
        gld_lds16(s + 8 * (long)lda, d + 1024);
    };
    auto stageB = [&](int t, int hh) {
        if (t >= NT) return;
        const u16* s = bG + (long)hh * 128 * ldb + (long)t * 64;
        char* d = lds + (t & 1) * 65536 + 32768 + hh * 16384 + w * 2048;
        gld_lds16(s, d);
        gld_lds16(s + 8 * (long)ldb, d + 1024);
    };

    const int rl    = lane & 15;
    const int kbyte = (lane >> 4) * 16;
    auto ldA = [&](int cur, int m, int kh) -> bf16x8 {
        const int row = wm * 128 + m * 16 + rl;
        const int byt = (kh * 64 + kbyte) ^ ((row & 7) << 4);
        return *(const bf16x8*)(lds + cur * 65536 + row * 128 + byt);
    };
    auto ldB = [&](int cur, int n, int kh) -> bf16x8 {
        const int row = wn * 64 + n * 16 + rl;
        const int byt = (kh * 64 + kbyte) ^ ((row & 7) << 4);
        return *(const bf16x8*)(lds + cur * 65536 + 32768 + row * 128 + byt);
    };

    f32x4 acc[8][4] = {};
    bf16x8 a0[4][2], a1[4][2], b0[2][2], b1[2][2];

    // prologue: tile0 fully + tile1 A-halves; leave A(1) pair in flight
    stageA(0, 0); stageA(0, 1);
    stageB(0, 0); stageB(0, 1);
    stageA(1, 0); stageA(1, 1);
    asm volatile("s_waitcnt vmcnt(4)" ::: "memory");
    BARRIER();

    for (int t = 0; t < NT; ++t) {
        const int cur = t & 1;

        // ---- phase 0: read a0 (m0-3) + b0 (n0-1); stage B-half0 of t+1
#pragma unroll
        for (int m = 0; m < 4; ++m)
#pragma unroll
            for (int kh = 0; kh < 2; ++kh) a0[m][kh] = ldA(cur, m, kh);
#pragma unroll
        for (int n = 0; n < 2; ++n)
#pragma unroll
            for (int kh = 0; kh < 2; ++kh) b0[n][kh] = ldB(cur, n, kh);
        stageB(t + 1, 0);
        BARRIER();
        LGKM0();
        __builtin_amdgcn_s_setprio(1);
#pragma unroll
        for (int kh = 0; kh < 2; ++kh)
#pragma unroll
            for (int m = 0; m < 4; ++m)
#pragma unroll
                for (int n = 0; n < 2; ++n)
                    acc[m][n] = __builtin_amdgcn_mfma_f32_16x16x32_bf16(
                        a0[m][kh], b0[n][kh], acc[m][n], 0, 0, 0);
        __builtin_amdgcn_s_setprio(0);
        BARRIER();

        // ---- phase 1: read a1 (m4-7); stage B-half1 of t+1
#pragma unroll
        for (int m = 0; m < 4; ++m)
#pragma unroll
            for (int kh = 0; kh < 2; ++kh) a1[m][kh] = ldA(cur, m + 4, kh);
        stageB(t + 1, 1);
        BARRIER();
        LGKM0();
        __builtin_amdgcn_s_setprio(1);
#pragma unroll
        for (int kh = 0; kh < 2; ++kh)
#pragma unroll
            for (int m = 0; m < 4; ++m)
#pragma unroll
                for (int n = 0; n < 2; ++n)
                    acc[m + 4][n] = __builtin_amdgcn_mfma_f32_16x16x32_bf16(
                        a1[m][kh], b0[n][kh], acc[m + 4][n], 0, 0, 0);
        __builtin_amdgcn_s_setprio(0);
        BARRIER();

        // ---- phase 2: read b1 (n2-3); stage A-half0 of t+2
#pragma unroll
        for (int n = 0; n < 2; ++n)
#pragma unroll
            for (int kh = 0; kh < 2; ++kh) b1[n][kh] = ldB(cur, n + 2, kh);
        stageA(t + 2, 0);
        BARRIER();
        LGKM0();
        __builtin_amdgcn_s_setprio(1);
#pragma unroll
        for (int kh = 0; kh < 2; ++kh)
#pragma unroll
            for (int m = 0; m < 4; ++m)
#pragma unroll
                for (int n = 0; n < 2; ++n)
                    acc[m + 4][n + 2] = __builtin_amdgcn_mfma_f32_16x16x32_bf16(
                        a1[m][kh], b1[n][kh], acc[m + 4][n + 2], 0, 0, 0);
        __builtin_amdgcn_s_setprio(0);
        BARRIER();

        // ---- phase 3: stage A-half1 of t+2; MFMA m0-3 x n2-3; boundary vmcnt
        stageA(t + 2, 1);
        BARRIER();
        __builtin_amdgcn_s_setprio(1);
#pragma unroll
        for (int kh = 0; kh < 2; ++kh)
#pragma unroll
            for (int m = 0; m < 4; ++m)
#pragma unroll
                for (int n = 0; n < 2; ++n)
                    acc[m][n + 2] = __builtin_amdgcn_mfma_f32_16x16x32_bf16(
                        a0[m][kh], b1[n][kh], acc[m][n + 2], 0, 0, 0);
        __builtin_amdgcn_s_setprio(0);
        if (t < NT - 2) { asm volatile("s_waitcnt vmcnt(4)" ::: "memory"); }
        else            { asm volatile("s_waitcnt vmcnt(0)" ::: "memory"); }
        BARRIER();
    }

    // epilogue: C/D layout col = lane&15, row = (lane>>4)*4 + j
#pragma unroll
    for (int m = 0; m < 8; ++m) {
#pragma unroll
        for (int n = 0; n < 4; ++n) {
            const long row0 = rowA0 + wm * 128 + m * 16 + (lane >> 4) * 4;
            const long col  = rowB0 + wn * 64 + n * 16 + (lane & 15);
            float bv = 0.0f;
            if (BIAS) bv = bias[col];
#pragma unroll
            for (int j = 0; j < 4; ++j) {
                const float val = acc[m][n][j] * scale + bv;
                const long  idx = (long)zb * sCb + (row0 + j) * ldc + col;
                if (BF16OUT) ((u16*)Cv)[idx] = f2bf(val);
                else         ((float*)Cv)[idx] = val;
            }
        }
    }
}

// ---------------------------------------------------------------------------
// In-place row softmax over 2048 bf16. One block (256 thr) per row.
// ---------------------------------------------------------------------------
__global__ __launch_bounds__(256)
void softmax_rows_bf16(u16* __restrict__ sc)
{
    __shared__ float redmax[4];
    __shared__ float redsum[4];
    const long row = blockIdx.x;
    u16x8* p = (u16x8*)(sc + row * 2048);
    const int t = threadIdx.x;

    u16x8 v = p[t];
    float f[8];
#pragma unroll
    for (int j = 0; j < 8; ++j) f[j] = bf2f(v[j]);

    float m = f[0];
#pragma unroll
    for (int j = 1; j < 8; ++j) m = fmaxf(m, f[j]);
#pragma unroll
    for (int o = 32; o; o >>= 1) m = fmaxf(m, __shfl_xor(m, o));
    if ((t & 63) == 0) redmax[t >> 6] = m;
    __syncthreads();
    m = fmaxf(fmaxf(redmax[0], redmax[1]), fmaxf(redmax[2], redmax[3]));

    float e[8], s = 0.0f;
#pragma unroll
    for (int j = 0; j < 8; ++j) { e[j] = __expf(f[j] - m); s += e[j]; }
#pragma unroll
    for (int o = 32; o; o >>= 1) s += __shfl_xor(s, o);
    if ((t & 63) == 0) redsum[t >> 6] = s;
    __syncthreads();
    s = redsum[0] + redsum[1] + redsum[2] + redsum[3];
    const float inv = 1.0f / s;

    u16x8 o;
#pragma unroll
    for (int j = 0; j < 8; ++j) o[j] = f2bf(e[j] * inv);
    p[t] = o;
}

// f32 -> bf16 elementwise, 4 elems/thread
__global__ __launch_bounds__(256)
void cvt_bf16(const float* __restrict__ src, u16* __restrict__ dst, long n4)
{
    const long i = (long)blockIdx.x * 256 + threadIdx.x;
    if (i >= n4) return;
    f32x4 v = ((const f32x4*)src)[i];
    u16x4 o;
#pragma unroll
    for (int j = 0; j < 4; ++j) o[j] = f2bf(v[j]);
    ((u16x4*)dst)[i] = o;
}

// x[b][n][d] f32 -> xb[b][n][d] bf16 (straight) + xT[b][d][n] bf16 (transposed)
__global__ __launch_bounds__(256)
void prep_x(const float* __restrict__ x, u16* __restrict__ xb, u16* __restrict__ xT)
{
    __shared__ float tile[32][33];
    const int  b  = blockIdx.z;
    const long n0 = (long)blockIdx.x * 32;
    const long d0 = (long)blockIdx.y * 32;
    const int  t  = threadIdx.x;
    const int  r  = t >> 3;
    const int  c  = (t & 7) * 4;

    f32x4 v = *(const f32x4*)(x + ((long)b * 2048 + n0 + r) * 1024 + d0 + c);
    u16x4 s;
#pragma unroll
    for (int j = 0; j < 4; ++j) { s[j] = f2bf(v[j]); tile[r][c + j] = v[j]; }
    *(u16x4*)(xb + ((long)b * 2048 + n0 + r) * 1024 + d0 + c) = s;
    __syncthreads();

    u16x4 o;
#pragma unroll
    for (int j = 0; j < 4; ++j) o[j] = f2bf(tile[c + j][r]);
    *(u16x4*)(xT + ((long)b * 1024 + d0 + r) * 2048 + n0 + c) = o;
}

// ---------------------------------------------------------------------------
// B=8, N=2048, DIM=1024.  ws layout (160 MB, fits the proven 164 MB budget):
//   xT [8,1024,2048] bf16 @ 0      (32 MB)  live: prep -> PV
//   qk [16384,2048]  bf16 @ 32 MB  (64 MB)  live: proj -> scores
//   sc [8,2048,2048] bf16 @ 96 MB  (64 MB)  scores -> softmax -> PV
//   xb [8,2048,1024] bf16 @ 96 MB  (32 MB)  ALIAS under sc; dead before scores
//   Wb [2048,1024]   bf16 @ 128 MB ( 4 MB)  ALIAS under sc; dead before scores
// ---------------------------------------------------------------------------
extern "C" void kernel_launch(void* const* d_in, const int* in_sizes, int n_in,
                              void* d_out, int out_size, void* d_ws, size_t ws_size,
                              hipStream_t stream)
{
    const float* x   = (const float*)d_in[0];
    const float* Wqk = (const float*)d_in[1];
    const float* bqk = (const float*)d_in[2];
    float* out = (float*)d_out;

    char* ws = (char*)d_ws;
    u16* xT = (u16*)(ws);
    u16* qk = (u16*)(ws + 33554432L);
    u16* sc = (u16*)(ws + 100663296L);
    u16* xb = (u16*)(ws + 100663296L);
    u16* Wb = (u16*)(ws + 134217728L);

    cvt_bf16<<<2048, 256, 0, stream>>>(Wqk, Wb, 2048L * 1024 / 4);
    prep_x<<<dim3(64, 32, 8), 256, 0, stream>>>(x, xb, xT);

    // qk = x @ W^T + b  -> bf16 [16384, 2048]
    gemm256<1, 1><<<dim3(64, 8, 1), 512, 0, stream>>>(
        xb, Wb, qk, bqk, 1024, 1024, 1024, 2048, 0, 0, 0, 1.0f);

    // sc[b] = k_b @ q_b^T / 32 -> bf16 [2048, 2048] per batch
    gemm256<1, 0><<<dim3(8, 8, 8), 512, 0, stream>>>(
        qk + 1024, qk, sc, nullptr, 1024, 2048, 2048, 2048,
        2048L * 2048, 2048L * 2048, 2048L * 2048, 0.03125f);

    // sc = softmax(sc) in place
    softmax_rows_bf16<<<16384, 256, 0, stream>>>(sc);

    // out[b] = attn_b @ x_b  (NT with xT) -> f32 to d_out
    gemm256<0, 0><<<dim3(8, 4, 8), 512, 0, stream>>>(
        sc, xT, out, nullptr, 2048, 2048, 2048, 1024,
        2048L * 2048, 1024L * 2048, 2048L * 1024, 1.0f);
}